// Round 1
// baseline (890.661 us; speedup 1.0000x reference)
//
#include <hip/hip_runtime.h>
#include <hip/hip_bf16.h>
#include <math.h>

#define H 128
#define TILE_M 64
#define LDS_STRIDE 136  // bf16 elems per LDS row: 272B, multiple of 16B, breaks power-of-2 banks

typedef __attribute__((ext_vector_type(8))) short bf16x8;
typedef __attribute__((ext_vector_type(4))) float f32x4;

__device__ __forceinline__ short f2bf(float f) {
  union { float f; unsigned u; } v; v.f = f;
  unsigned r = v.u + 0x7fffu + ((v.u >> 16) & 1u);  // round-to-nearest-even
  return (short)(r >> 16);
}

// ---- K0: W1 (fp32, [k][n]) -> W1T bf16 [n][k], so B-frags are contiguous 16B ----
__global__ void prep_kernel(const float* __restrict__ w1, short* __restrict__ w1t) {
  int i = blockIdx.x * blockDim.x + threadIdx.x;   // 0 .. H*H-1
  if (i >= H * H) return;
  int k = i >> 7, n = i & (H - 1);
  w1t[n * H + k] = f2bf(w1[k * H + n]);
}

// ---- K1: segment boundaries from sorted batch_index. seg_start[g] = lower_bound(bi, g) ----
__global__ void bounds_kernel(const int* __restrict__ bi, int* __restrict__ seg_start,
                              int N, int B) {
  int n = blockIdx.x * blockDim.x + threadIdx.x;
  if (n >= N) return;
  int cur = bi[n];
  int prev = (n == 0) ? -1 : bi[n - 1];
  for (int g = prev + 1; g <= cur; ++g) seg_start[g] = n;
  if (n == N - 1) {
    for (int g = cur + 1; g <= B; ++g) seg_start[g] = N;
  }
}

// ---- K2: gate[n] = silu(x@W1 + b1) @ W2 + b2, bf16 MFMA ----
__global__ __launch_bounds__(256) void gate_kernel(
    const float* __restrict__ x, const short* __restrict__ w1t,
    const float* __restrict__ b1, const float* __restrict__ w2,
    const float* __restrict__ b2, float* __restrict__ gate, int N)
{
  __shared__ __align__(16) short xs[TILE_M * LDS_STRIDE];
  __shared__ float gate_lds[TILE_M];

  const int tid = threadIdx.x;
  const int base = blockIdx.x * TILE_M;

  if (tid < TILE_M) gate_lds[tid] = 0.0f;

  // stage x tile fp32 -> bf16 LDS (coalesced float4 reads: wave reads 1KB contiguous)
  {
    const int colg = (tid & 31) * 4;
    const int row0 = tid >> 5;  // 0..7
#pragma unroll
    for (int i = 0; i < 8; ++i) {
      int row = row0 + 8 * i;
      int gr = base + row;
      float4 v = make_float4(0.f, 0.f, 0.f, 0.f);
      if (gr < N) v = *(const float4*)(x + (size_t)gr * H + colg);
      short4 s = make_short4(f2bf(v.x), f2bf(v.y), f2bf(v.z), f2bf(v.w));
      *(short4*)(&xs[row * LDS_STRIDE + colg]) = s;
    }
  }
  __syncthreads();

  const int w = tid >> 6;        // wave 0..3 -> columns [32w, 32w+32)
  const int lane = tid & 63;
  const int l15 = lane & 15;
  const int q = lane >> 4;       // quad 0..3

  f32x4 acc[4][2] = {};
#pragma unroll
  for (int kc = 0; kc < H; kc += 32) {
    bf16x8 a[4], b[2];
#pragma unroll
    for (int mt = 0; mt < 4; ++mt) {
      // A[m][k]: m = lane&15 (+16*mt), k = kc + 8*q + j  (contiguous 16B)
      a[mt] = *(const bf16x8*)(&xs[(16 * mt + l15) * LDS_STRIDE + kc + 8 * q]);
    }
#pragma unroll
    for (int nt = 0; nt < 2; ++nt) {
      // B[k][n]: n = lane&15 (+offset), k = kc + 8*q + j ; W1T[n][k] contiguous 16B
      int n = 32 * w + 16 * nt + l15;
      b[nt] = *(const bf16x8*)(w1t + n * H + kc + 8 * q);
    }
#pragma unroll
    for (int mt = 0; mt < 4; ++mt)
#pragma unroll
      for (int nt = 0; nt < 2; ++nt)
        acc[mt][nt] = __builtin_amdgcn_mfma_f32_16x16x32_bf16(a[mt], b[nt], acc[mt][nt], 0, 0, 0);
  }

  // epilogue: h += b1; silu; * W2[col]; reduce over the 16 lanes holding one row's cols
  const int c0 = 32 * w + l15;
  const int c1 = c0 + 16;
  const float w2c0 = w2[c0], w2c1 = w2[c1];
  const float b1c0 = b1[c0], b1c1 = b1[c1];
#pragma unroll
  for (int mt = 0; mt < 4; ++mt) {
#pragma unroll
    for (int r = 0; r < 4; ++r) {
      float h0 = acc[mt][0][r] + b1c0;
      float h1 = acc[mt][1][r] + b1c1;
      float s0 = h0 / (1.0f + __expf(-h0));
      float s1 = h1 / (1.0f + __expf(-h1));
      float p = s0 * w2c0 + s1 * w2c1;
      p += __shfl_xor(p, 1);
      p += __shfl_xor(p, 2);
      p += __shfl_xor(p, 4);
      p += __shfl_xor(p, 8);
      if (l15 == 0) atomicAdd(&gate_lds[16 * mt + 4 * q + r], p);
    }
  }
  __syncthreads();
  if (tid < TILE_M) {
    int gr = base + tid;
    if (gr < N) gate[gr] = gate_lds[tid] + b2[0];
  }
}

// ---- K3: per-graph single pass: mean, max, online-softmax attention ----
__global__ __launch_bounds__(128) void pool_kernel(
    const float* __restrict__ x, const float* __restrict__ gate,
    const int* __restrict__ seg_start, float* __restrict__ out)
{
  const int g = blockIdx.x;
  const int h = threadIdx.x;
  const int s = seg_start[g];
  const int e = seg_start[g + 1];

  float sum = 0.f, mx = -INFINITY;
  float accv = 0.f, m_run = -INFINITY, l_run = 0.f;

  for (int n = s; n < e; ++n) {
    float xv = x[(size_t)n * H + h];
    float gt = gate[n];
    sum += xv;
    mx = fmaxf(mx, xv);
    float m_new = fmaxf(m_run, gt);
    float corr = __expf(m_run - m_new);   // first iter: exp(-inf)=0
    float ev = __expf(gt - m_new);
    l_run = l_run * corr + ev;
    accv = accv * corr + ev * xv;
    m_run = m_new;
  }

  const int cnt = e - s;
  float* og = out + (size_t)g * (3 * H);
  og[h] = sum / fmaxf((float)cnt, 1.0f);
  og[H + h] = mx;                                  // -inf for empty segment (segment_max identity)
  og[2 * H + h] = (cnt > 0) ? (accv / l_run) : 0.0f;
}

extern "C" void kernel_launch(void* const* d_in, const int* in_sizes, int n_in,
                              void* d_out, int out_size, void* d_ws, size_t ws_size,
                              hipStream_t stream)
{
  const float* x   = (const float*)d_in[0];
  const float* w1  = (const float*)d_in[1];
  const float* b1  = (const float*)d_in[2];
  const float* w2  = (const float*)d_in[3];
  const float* b2  = (const float*)d_in[4];
  const int*  bidx = (const int*)d_in[5];

  const int N  = in_sizes[5];            // batch_index length
  const int Bn = out_size / (3 * H);     // num graphs

  // workspace layout
  char* ws = (char*)d_ws;
  size_t off = 0;
  float* gate = (float*)(ws + off);
  off += (size_t)N * sizeof(float);
  off = (off + 255) & ~(size_t)255;
  int* seg_start = (int*)(ws + off);
  off += (size_t)(Bn + 1) * sizeof(int);
  off = (off + 255) & ~(size_t)255;
  short* w1t = (short*)(ws + off);

  prep_kernel<<<(H * H + 255) / 256, 256, 0, stream>>>(w1, w1t);
  bounds_kernel<<<(N + 255) / 256, 256, 0, stream>>>(bidx, seg_start, N, Bn);
  gate_kernel<<<(N + TILE_M - 1) / TILE_M, 256, 0, stream>>>(x, w1t, b1, w2, b2, gate, N);
  pool_kernel<<<Bn, H, 0, stream>>>(x, gate, seg_start, (float*)d_out);
}

// Round 3
// 885.630 us; speedup vs baseline: 1.0057x; 1.0057x over previous
//
#include <hip/hip_runtime.h>
#include <hip/hip_bf16.h>
#include <math.h>

#define H 128
#define TILE 64
#define XB_STRIDE 136   // bf16 elems per LDS row: 272B -> lane i hits banks 4i..4i+3 mod 32 (2-way, free)

typedef __attribute__((ext_vector_type(8))) short bf16x8;
typedef __attribute__((ext_vector_type(4))) float f32x4;

__device__ __forceinline__ short f2bf(float f) {
  union { float f; unsigned u; } v; v.f = f;
  unsigned r = v.u + 0x7fffu + ((v.u >> 16) & 1u);  // round-to-nearest-even
  return (short)(r >> 16);
}

// ---- K0: W1 (fp32, [k][n]) -> W1T bf16 [n][k], so B-frags are contiguous 16B ----
__global__ void prep_kernel(const float* __restrict__ w1, short* __restrict__ w1t) {
  int i = blockIdx.x * blockDim.x + threadIdx.x;   // 0 .. H*H-1
  if (i >= H * H) return;
  int k = i >> 7, n = i & (H - 1);
  w1t[n * H + k] = f2bf(w1[k * H + n]);
}

// ---- K1: segment boundaries from sorted batch_index ----
__global__ void bounds_kernel(const int* __restrict__ bi, int* __restrict__ seg_start,
                              int N, int B) {
  int n = blockIdx.x * blockDim.x + threadIdx.x;
  if (n >= N) return;
  int cur = bi[n];
  int prev = (n == 0) ? -1 : bi[n - 1];
  for (int g = prev + 1; g <= cur; ++g) seg_start[g] = n;
  if (n == N - 1) {
    for (int g = cur + 1; g <= B; ++g) seg_start[g] = N;
  }
}

// ---- K2: fused per-graph readout: gate MLP (MFMA) + mean/max/attn pooling, x read ONCE ----
__global__ __launch_bounds__(256) void fused_kernel(
    const float* __restrict__ x, const short* __restrict__ w1t,
    const float* __restrict__ b1, const float* __restrict__ w2,
    const float* __restrict__ b2, const int* __restrict__ seg_start,
    float* __restrict__ out)
{
  __shared__ __align__(16) float xf[TILE][H];            // 32 KB fp32 tile (pool scan)
  __shared__ __align__(16) short xb[TILE * XB_STRIDE];   // 17 KB bf16 tile (MFMA A)
  __shared__ float gate_lds[TILE];
  __shared__ float merge_lds[5][H];                      // half-merge buffer

  const int g = blockIdx.x;
  const int s = seg_start[g];
  const int e = seg_start[g + 1];
  const int R = e - s;

  const int tid  = threadIdx.x;
  const int w    = tid >> 6;       // wave 0..3 -> cols [32w, 32w+32)
  const int lane = tid & 63;
  const int l15  = lane & 15;
  const int q    = lane >> 4;

  // pool split: h = feature, half = which rows (even/odd)
  const int h    = tid & (H - 1);
  const int half = tid >> 7;
  float sum = 0.f, mx = -INFINITY;
  float m_run = -INFINITY, l_run = 0.f, accv = 0.f;

  const float b2v  = b2[0];
  const int   c0   = 32 * w + l15, c1 = c0 + 16;
  const float w2c0 = w2[c0], w2c1 = w2[c1];
  const float b1c0 = b1[c0], b1c1 = b1[c1];

  for (int t0 = 0; t0 < R; t0 += TILE) {
    const int Rt = min(TILE, R - t0);

    // ---- stage: global fp32 -> LDS fp32 + bf16 (coalesced float4, rows contiguous) ----
    {
      const int colg = (tid & 31) * 4;
      const int row0 = tid >> 5;   // 0..7
#pragma unroll
      for (int i = 0; i < 8; ++i) {
        int row = row0 + 8 * i;
        float4 v = make_float4(0.f, 0.f, 0.f, 0.f);
        if (row < Rt) v = *(const float4*)(x + (size_t)(s + t0 + row) * H + colg);
        *(float4*)(&xf[row][colg]) = v;
        short4 sv = make_short4(f2bf(v.x), f2bf(v.y), f2bf(v.z), f2bf(v.w));
        *(short4*)(&xb[row * XB_STRIDE + colg]) = sv;
      }
    }
    if (tid < TILE) gate_lds[tid] = 0.0f;
    __syncthreads();

    // ---- gate GEMM: 64x128 @ 128x128, bf16 MFMA ----
    f32x4 acc[4][2] = {};
#pragma unroll
    for (int kc = 0; kc < H; kc += 32) {
      bf16x8 a[4], b[2];
#pragma unroll
      for (int mt = 0; mt < 4; ++mt)
        a[mt] = *(const bf16x8*)(&xb[(16 * mt + l15) * XB_STRIDE + kc + 8 * q]);
#pragma unroll
      for (int nt = 0; nt < 2; ++nt) {
        int n = 32 * w + 16 * nt + l15;
        b[nt] = *(const bf16x8*)(w1t + n * H + kc + 8 * q);
      }
#pragma unroll
      for (int mt = 0; mt < 4; ++mt)
#pragma unroll
        for (int nt = 0; nt < 2; ++nt)
          acc[mt][nt] = __builtin_amdgcn_mfma_f32_16x16x32_bf16(a[mt], b[nt], acc[mt][nt], 0, 0, 0);
    }

    // ---- epilogue: silu(h)*W2, reduce 16 lanes -> per-row partial, atomicAdd into LDS ----
#pragma unroll
    for (int mt = 0; mt < 4; ++mt) {
#pragma unroll
      for (int r = 0; r < 4; ++r) {
        float h0 = acc[mt][0][r] + b1c0;
        float h1 = acc[mt][1][r] + b1c1;
        float s0 = h0 / (1.0f + __expf(-h0));
        float s1 = h1 / (1.0f + __expf(-h1));
        float p = s0 * w2c0 + s1 * w2c1;
        p += __shfl_xor(p, 1);
        p += __shfl_xor(p, 2);
        p += __shfl_xor(p, 4);
        p += __shfl_xor(p, 8);
        if (l15 == 0) atomicAdd(&gate_lds[16 * mt + 4 * q + r], p);
      }
    }
    __syncthreads();

    // ---- pool scan over this tile's rows (halves interleave rows) ----
    for (int r = half; r < Rt; r += 2) {
      float gt = gate_lds[r] + b2v;        // LDS broadcast
      float xv = xf[r][h];
      sum += xv;
      mx = fmaxf(mx, xv);
      float m_new = fmaxf(m_run, gt);
      float corr = __expf(m_run - m_new);  // first iter: exp(-inf)=0
      float ev   = __expf(gt - m_new);
      l_run = l_run * corr + ev;
      accv  = accv * corr + ev * xv;
      m_run = m_new;
    }
    __syncthreads();   // scan done before next tile overwrites LDS
  }

  // ---- merge the two halves' online states ----
  if (half == 1) {
    merge_lds[0][h] = sum;
    merge_lds[1][h] = mx;
    merge_lds[2][h] = m_run;
    merge_lds[3][h] = l_run;
    merge_lds[4][h] = accv;
  }
  __syncthreads();
  if (half == 0) {
    float sum2 = merge_lds[0][h], mx2 = merge_lds[1][h];
    float m2 = merge_lds[2][h], l2 = merge_lds[3][h], a2 = merge_lds[4][h];
    sum += sum2;
    mx = fmaxf(mx, mx2);
    // R>=1 guarantees half0 saw row 0 => m_run finite; cB handles l2==0 (m2=-inf) -> 0
    float m_new = fmaxf(m_run, m2);
    float cA = __expf(m_run - m_new);
    float cB = __expf(m2 - m_new);
    l_run = l_run * cA + l2 * cB;
    accv  = accv * cA + a2 * cB;

    float* og = out + (size_t)g * (3 * H);
    og[h]         = sum / fmaxf((float)R, 1.0f);
    og[H + h]     = mx;                                  // -inf for empty segment
    og[2 * H + h] = (R > 0) ? (accv / l_run) : 0.0f;
  }
}

extern "C" void kernel_launch(void* const* d_in, const int* in_sizes, int n_in,
                              void* d_out, int out_size, void* d_ws, size_t ws_size,
                              hipStream_t stream)
{
  const float* x   = (const float*)d_in[0];
  const float* w1  = (const float*)d_in[1];
  const float* b1  = (const float*)d_in[2];
  const float* w2  = (const float*)d_in[3];
  const float* b2  = (const float*)d_in[4];
  const int*  bidx = (const int*)d_in[5];

  const int N  = in_sizes[5];            // batch_index length
  const int Bn = out_size / (3 * H);     // num graphs

  // workspace: seg_start then w1t
  char* ws = (char*)d_ws;
  size_t off = 0;
  int* seg_start = (int*)(ws + off);
  off += (size_t)(Bn + 1) * sizeof(int);
  off = (off + 255) & ~(size_t)255;
  short* w1t = (short*)(ws + off);

  prep_kernel<<<(H * H + 255) / 256, 256, 0, stream>>>(w1, w1t);
  bounds_kernel<<<(N + 255) / 256, 256, 0, stream>>>(bidx, seg_start, N, Bn);
  fused_kernel<<<Bn, 256, 0, stream>>>(x, w1t, b1, w2, b2, seg_start, (float*)d_out);
}